// Round 2
// baseline (324.809 us; speedup 1.0000x reference)
//
#include <hip/hip_runtime.h>

// YOLOv1 loss, faithful to the reference (including the in-place corner bug).
// R2: stage only T in LDS (30 KB/block -> 5 blocks/CU, 62% occupancy cap);
// P cols 0..9 loaded per-thread as float2, p[kcol] as one dynamic dword.

constexpr int   BS   = 256;            // cells per block (threads per block)
constexpr int   NC   = 16384 * 7 * 7;  // 802816 cells
constexpr float CELL = 1.0f / 7.0f;
constexpr float LC   = 5.0f;
constexpr float LN   = 0.5f;

__global__ void zero4(float* __restrict__ out) {
    if (threadIdx.x < 4) out[threadIdx.x] = 0.0f;
}

__launch_bounds__(BS, 5)
__global__ void yolo_loss(const float* __restrict__ P, const float* __restrict__ T,
                          float* __restrict__ out)
{
    __shared__ float sT[BS * 30];          // 30720 B
    __shared__ float red[4][BS / 64];

    const int tid  = threadIdx.x;
    const size_t base = (size_t)blockIdx.x * (BS * 30);

    // ---- per-thread P loads (cols 0..9), 8B-aligned float2, wave-contiguous ----
    const float* prow = P + base + (size_t)tid * 30;
    float pv[10];
    #pragma unroll
    for (int j = 0; j < 5; ++j) {
        float2 v = reinterpret_cast<const float2*>(prow)[j];
        pv[2 * j] = v.x; pv[2 * j + 1] = v.y;
    }

    // ---- cooperative coalesced staging of T into LDS: float4 loads ----
    const float4* gT4 = reinterpret_cast<const float4*>(T + base);
    float4* sT4 = reinterpret_cast<float4*>(sT);
    constexpr int NV4 = BS * 30 / 4;  // 1920 float4
    #pragma unroll
    for (int k = 0; k < (NV4 + BS - 1) / BS; ++k) {
        int idx = k * BS + tid;
        if (idx < NV4) sT4[idx] = gT4[idx];
    }
    __syncthreads();

    // ---- per-cell T from LDS (stride 30 dwords -> 2-way bank alias, free) ----
    const float* tt = sT + tid * 30;
    float tv[30];
    #pragma unroll
    for (int j = 0; j < 15; ++j) {
        float2 v = reinterpret_cast<const float2*>(tt)[j];
        tv[2 * j] = v.x; tv[2 * j + 1] = v.y;
    }

    // class column: argmax over t[10:30], first occurrence, strict >
    int kc = 10;
    float best = tv[10];
    #pragma unroll
    for (int k = 11; k < 30; ++k) {
        if (tv[k] > best) { best = tv[k]; kc = k; }
    }
    // issue the dynamic P load early; latency hidden by the IoU math below
    float pk = prow[kc];

    const float t4 = tv[4];
    const float obj   = (t4 == 1.0f) ? 1.0f : 0.0f;
    const float noobj = (t4 == 0.0f) ? 1.0f : 0.0f;

    // no-object confidence loss (cols 4 and 9), unscaled partial
    float d4 = pv[4] - t4;
    float d9 = pv[9] - tv[9];
    float noobj_v = noobj * (d4 * d4 + d9 * d9);

    // target box corners (faithful bug: x2 uses already-updated x1)
    float tw2 = tv[2] * tv[2], th2 = tv[3] * tv[3];
    float tx1 = tv[0] * CELL - 0.5f * tw2;
    float tx2 = tx1 * CELL + 0.5f * tw2;
    float ty1 = tv[1] * CELL - 0.5f * th2;
    float ty2 = ty1 * CELL + 0.5f * th2;
    float area_t = (tx2 - tx1) * (ty2 - ty1);

    float iou0, iou1;
    #pragma unroll
    for (int b = 0; b < 2; ++b) {
        float bx = pv[5 * b + 0], by = pv[5 * b + 1];
        float bw2 = pv[5 * b + 2] * pv[5 * b + 2];
        float bh2 = pv[5 * b + 3] * pv[5 * b + 3];
        float px1 = bx * CELL - 0.5f * bw2;
        float px2 = px1 * CELL + 0.5f * bw2;
        float py1 = by * CELL - 0.5f * bh2;
        float py2 = py1 * CELL + 0.5f * bh2;
        float ltx = fmaxf(px1, tx1), lty = fmaxf(py1, ty1);
        float rbx = fminf(px2, tx2), rby = fminf(py2, ty2);
        float inter = fmaxf(rbx - ltx, 0.0f) * fmaxf(rby - lty, 0.0f);
        float area_p = (px2 - px1) * (py2 - py1);
        float iou = inter / (area_p + area_t - inter);
        if (b == 0) iou0 = iou; else iou1 = iou;
    }
    // jnp.argmax: first occurrence on ties -> strict >
    const bool b1 = (iou1 > iou0);

    float cpx = b1 ? pv[5] : pv[0], ctx = b1 ? tv[5] : tv[0];
    float cpy = b1 ? pv[6] : pv[1], cty = b1 ? tv[6] : tv[1];
    float cpw = b1 ? pv[7] : pv[2], ctw = b1 ? tv[7] : tv[2];
    float cph = b1 ? pv[8] : pv[3], cth = b1 ? tv[8] : tv[3];
    float cpc = b1 ? pv[9] : pv[4], ctc = b1 ? tv[9] : tv[4];

    float dx = cpx - ctx, dy = cpy - cty;
    float dw = cpw - ctw, dh = cph - cth;
    float cw_v = obj * (dx * dx + dy * dy + dw * dw + dh * dh);  // center + wh
    float dc = cpc - ctc;
    float conf_v = obj * dc * dc;

    float dk = pk - best;
    float cls_v = obj * dk * dk;

    // ---- reduction: wave (64) -> block -> global atomics ----
    float vals[4] = { cls_v, conf_v, cw_v, noobj_v };
    #pragma unroll
    for (int c = 0; c < 4; ++c) {
        float v = vals[c];
        #pragma unroll
        for (int off = 32; off > 0; off >>= 1)
            v += __shfl_down(v, off, 64);
        if ((tid & 63) == 0) red[c][tid >> 6] = v;
    }
    __syncthreads();
    if (tid == 0) {
        float s[4];
        #pragma unroll
        for (int c = 0; c < 4; ++c) {
            float acc = 0.0f;
            #pragma unroll
            for (int w = 0; w < BS / 64; ++w) acc += red[c][w];
            s[c] = acc;
        }
        atomicAdd(&out[0], LC * s[0]);                              // cls_loss
        atomicAdd(&out[1], LC * s[1]);                              // conf_loss
        atomicAdd(&out[2], LC * s[2]);                              // center+wh
        atomicAdd(&out[3], LN * s[3] + LC * (s[0] + s[1] + s[2]));  // total
    }
}

extern "C" void kernel_launch(void* const* d_in, const int* in_sizes, int n_in,
                              void* d_out, int out_size, void* d_ws, size_t ws_size,
                              hipStream_t stream) {
    const float* P = (const float*)d_in[0];
    const float* T = (const float*)d_in[1];
    float* out = (float*)d_out;

    zero4<<<1, 64, 0, stream>>>(out);                 // harness poisons d_out
    yolo_loss<<<NC / BS, BS, 0, stream>>>(P, T, out);
}

// Round 3
// 209.688 us; speedup vs baseline: 1.5490x; 1.5490x over previous
//
#include <hip/hip_runtime.h>

// YOLOv1 loss, faithful to the reference (including the in-place corner bug).
// R3: kill the same-address atomic serialization (3136 blocks x 4 atomicAdd on
// one cache line ~= 185 us drain at L2). Blocks store float4 partials to d_ws;
// a 1-block reduce kernel sums 3136 partials and writes the 4 outputs.

constexpr int   BS   = 256;            // cells per block (threads per block)
constexpr int   NC   = 16384 * 7 * 7;  // 802816 cells
constexpr int   NB   = NC / BS;        // 3136 blocks
constexpr float CELL = 1.0f / 7.0f;
constexpr float LC   = 5.0f;
constexpr float LN   = 0.5f;

__launch_bounds__(BS, 5)
__global__ void yolo_partial(const float* __restrict__ P, const float* __restrict__ T,
                             float4* __restrict__ ws)
{
    __shared__ float sT[BS * 30];          // 30720 B
    __shared__ float red[4][BS / 64];

    const int tid  = threadIdx.x;
    const size_t base = (size_t)blockIdx.x * (BS * 30);

    // ---- per-thread P loads (cols 0..9), 8B-aligned float2, wave-contiguous ----
    const float* prow = P + base + (size_t)tid * 30;
    float pv[10];
    #pragma unroll
    for (int j = 0; j < 5; ++j) {
        float2 v = reinterpret_cast<const float2*>(prow)[j];
        pv[2 * j] = v.x; pv[2 * j + 1] = v.y;
    }

    // ---- cooperative coalesced staging of T into LDS: float4 loads ----
    const float4* gT4 = reinterpret_cast<const float4*>(T + base);
    float4* sT4 = reinterpret_cast<float4*>(sT);
    constexpr int NV4 = BS * 30 / 4;  // 1920 float4
    #pragma unroll
    for (int k = 0; k < (NV4 + BS - 1) / BS; ++k) {
        int idx = k * BS + tid;
        if (idx < NV4) sT4[idx] = gT4[idx];
    }
    __syncthreads();

    // ---- per-cell T from LDS (stride 30 dwords -> 2-way bank alias, free) ----
    const float* tt = sT + tid * 30;
    float tv[30];
    #pragma unroll
    for (int j = 0; j < 15; ++j) {
        float2 v = reinterpret_cast<const float2*>(tt)[j];
        tv[2 * j] = v.x; tv[2 * j + 1] = v.y;
    }

    // class column: argmax over t[10:30], first occurrence, strict >
    int kc = 10;
    float best = tv[10];
    #pragma unroll
    for (int k = 11; k < 30; ++k) {
        if (tv[k] > best) { best = tv[k]; kc = k; }
    }
    // issue the dynamic P load early; latency hidden by the IoU math below
    float pk = prow[kc];

    const float t4 = tv[4];
    const float obj   = (t4 == 1.0f) ? 1.0f : 0.0f;
    const float noobj = (t4 == 0.0f) ? 1.0f : 0.0f;

    // no-object confidence loss (cols 4 and 9), unscaled partial
    float d4 = pv[4] - t4;
    float d9 = pv[9] - tv[9];
    float noobj_v = noobj * (d4 * d4 + d9 * d9);

    // target box corners (faithful bug: x2 uses already-updated x1)
    float tw2 = tv[2] * tv[2], th2 = tv[3] * tv[3];
    float tx1 = tv[0] * CELL - 0.5f * tw2;
    float tx2 = tx1 * CELL + 0.5f * tw2;
    float ty1 = tv[1] * CELL - 0.5f * th2;
    float ty2 = ty1 * CELL + 0.5f * th2;
    float area_t = (tx2 - tx1) * (ty2 - ty1);

    float iou0, iou1;
    #pragma unroll
    for (int b = 0; b < 2; ++b) {
        float bx = pv[5 * b + 0], by = pv[5 * b + 1];
        float bw2 = pv[5 * b + 2] * pv[5 * b + 2];
        float bh2 = pv[5 * b + 3] * pv[5 * b + 3];
        float px1 = bx * CELL - 0.5f * bw2;
        float px2 = px1 * CELL + 0.5f * bw2;
        float py1 = by * CELL - 0.5f * bh2;
        float py2 = py1 * CELL + 0.5f * bh2;
        float ltx = fmaxf(px1, tx1), lty = fmaxf(py1, ty1);
        float rbx = fminf(px2, tx2), rby = fminf(py2, ty2);
        float inter = fmaxf(rbx - ltx, 0.0f) * fmaxf(rby - lty, 0.0f);
        float area_p = (px2 - px1) * (py2 - py1);
        float iou = inter / (area_p + area_t - inter);
        if (b == 0) iou0 = iou; else iou1 = iou;
    }
    // jnp.argmax: first occurrence on ties -> strict >
    const bool b1 = (iou1 > iou0);

    float cpx = b1 ? pv[5] : pv[0], ctx = b1 ? tv[5] : tv[0];
    float cpy = b1 ? pv[6] : pv[1], cty = b1 ? tv[6] : tv[1];
    float cpw = b1 ? pv[7] : pv[2], ctw = b1 ? tv[7] : tv[2];
    float cph = b1 ? pv[8] : pv[3], cth = b1 ? tv[8] : tv[3];
    float cpc = b1 ? pv[9] : pv[4], ctc = b1 ? tv[9] : tv[4];

    float dx = cpx - ctx, dy = cpy - cty;
    float dw = cpw - ctw, dh = cph - cth;
    float cw_v = obj * (dx * dx + dy * dy + dw * dw + dh * dh);  // center + wh
    float dc = cpc - ctc;
    float conf_v = obj * dc * dc;

    float dk = pk - best;
    float cls_v = obj * dk * dk;

    // ---- reduction: wave (64) -> block -> one float4 store per block ----
    float vals[4] = { cls_v, conf_v, cw_v, noobj_v };
    #pragma unroll
    for (int c = 0; c < 4; ++c) {
        float v = vals[c];
        #pragma unroll
        for (int off = 32; off > 0; off >>= 1)
            v += __shfl_down(v, off, 64);
        if ((tid & 63) == 0) red[c][tid >> 6] = v;
    }
    __syncthreads();
    if (tid == 0) {
        float4 s;
        s.x = red[0][0] + red[0][1] + red[0][2] + red[0][3];
        s.y = red[1][0] + red[1][1] + red[1][2] + red[1][3];
        s.z = red[2][0] + red[2][1] + red[2][2] + red[2][3];
        s.w = red[3][0] + red[3][1] + red[3][2] + red[3][3];
        ws[blockIdx.x] = s;   // plain store, unique cache line per block
    }
}

__launch_bounds__(256, 1)
__global__ void yolo_reduce(const float4* __restrict__ ws, float* __restrict__ out)
{
    __shared__ float red[4][4];
    const int tid = threadIdx.x;

    float s0 = 0.f, s1 = 0.f, s2 = 0.f, s3 = 0.f;
    for (int b = tid; b < NB; b += 256) {          // coalesced float4 stream
        float4 v = ws[b];
        s0 += v.x; s1 += v.y; s2 += v.z; s3 += v.w;
    }
    float vals[4] = { s0, s1, s2, s3 };
    #pragma unroll
    for (int c = 0; c < 4; ++c) {
        float v = vals[c];
        #pragma unroll
        for (int off = 32; off > 0; off >>= 1)
            v += __shfl_down(v, off, 64);
        if ((tid & 63) == 0) red[c][tid >> 6] = v;
    }
    __syncthreads();
    if (tid == 0) {
        float t0 = red[0][0] + red[0][1] + red[0][2] + red[0][3];
        float t1 = red[1][0] + red[1][1] + red[1][2] + red[1][3];
        float t2 = red[2][0] + red[2][1] + red[2][2] + red[2][3];
        float t3 = red[3][0] + red[3][1] + red[3][2] + red[3][3];
        out[0] = LC * t0;                              // cls_loss
        out[1] = LC * t1;                              // conf_loss
        out[2] = LC * t2;                              // center+wh
        out[3] = LN * t3 + LC * (t0 + t1 + t2);        // total
    }
}

extern "C" void kernel_launch(void* const* d_in, const int* in_sizes, int n_in,
                              void* d_out, int out_size, void* d_ws, size_t ws_size,
                              hipStream_t stream) {
    const float* P = (const float*)d_in[0];
    const float* T = (const float*)d_in[1];
    float* out = (float*)d_out;
    float4* ws = (float4*)d_ws;          // NB * 16 B = 50176 B of scratch

    yolo_partial<<<NB, BS, 0, stream>>>(P, T, ws);
    yolo_reduce<<<1, 256, 0, stream>>>(ws, out);
}